// Round 4
// baseline (305.894 us; speedup 1.0000x reference)
//
#include <hip/hip_runtime.h>
#include <hip/hip_fp16.h>
#include <math.h>

#define N_NODES 100000
#define D_DIM   64
#define N_EDGES 1600000
#define P_L 0.5f
#define P_H 0.5f

#define NPB   32                       // nodes per bucket (exact: 32*3125=100000)
#define NB    3125                     // number of buckets
#define TILE  2048                     // edges per partition tile
#define NT    784                      // number of tiles
#define GRP   28                       // scan groups (GRP*GT == NT)
#define GT    28                       // tiles per scan group
#define CAP   768                      // per-bucket record capacity (mean 512, +11 sigma)
#define ZS    132                      // z row stride (16B-aligned rows, bank-spread)

// NOTE (round-1 lesson): LDS float atomicAdd (ds_add_f32) on gfx950 measured
// ~220 cy/wave-instr effective (~3 cy/lane serialized). Never on a hot path.
// NOTE (round-2 lesson): __launch_bounds__ min-waves pin below actual register
// pressure -> scratch spill (WRITE_SIZE 25->597 MB), 4x slowdown. No pins.
// NOTE (round-3 lesson): proven accum structure = counting-sort + batch-4
// register accumulation, 36 VGPR, 127 us. Stall split: phase-4 serial gather
// latency + sort-phase LDS-atomic serialization. This round: prefetch the
// gather set during the sort, wave-aggregate the atomics, pk-math the FMAs.

typedef unsigned int uint;
typedef unsigned short ushort_t;
typedef float f2 __attribute__((ext_vector_type(2)));   // -> v_pk_fma_f32

__device__ inline ushort_t f2bf(float f) {
    uint u = __float_as_uint(f);
    uint r = (u + 0x7fffu + ((u >> 16) & 1u)) >> 16;
    return (ushort_t)r;
}

// fast tanh for x >= 0
__device__ inline float tanh_pos(float x) {
    return 1.f - 2.f / (__expf(2.f * x) + 1.f);
}

// 16 FMAs of one record into the per-lane accumulator (8 x v_pk_fma_f32)
__device__ inline void fma16(uint gy, uint4 hv, f2* acc) {
    float el = __half2float(__ushort_as_half((unsigned short)(gy & 0xffffu)));
    float eh = __half2float(__ushort_as_half((unsigned short)(gy >> 16)));
    f2 f01 = {__uint_as_float(hv.x << 16), __uint_as_float(hv.x & 0xffff0000u)};
    f2 f23 = {__uint_as_float(hv.y << 16), __uint_as_float(hv.y & 0xffff0000u)};
    f2 f45 = {__uint_as_float(hv.z << 16), __uint_as_float(hv.z & 0xffff0000u)};
    f2 f67 = {__uint_as_float(hv.w << 16), __uint_as_float(hv.w & 0xffff0000u)};
    acc[0] += f01 * el; acc[1] += f23 * el; acc[2] += f45 * el; acc[3] += f67 * el;
    acc[4] += f01 * eh; acc[5] += f23 * eh; acc[6] += f45 * eh; acc[7] += f67 * eh;
}

// lanes-with-same-dl mask via 5 ballots (dl in [0,32)); valid on active lanes
__device__ inline unsigned long long match_dl(int dl, bool active) {
    unsigned long long m = __ballot(active);
    #pragma unroll
    for (int b = 0; b < 5; ++b) {
        unsigned long long bal = __ballot(active && ((dl >> b) & 1));
        m &= ((dl >> b) & 1) ? bal : ~bal;
    }
    return m;
}

// ---------------------------------------------------------------------------
// K1: per-node gate projections + h -> bf16. TWO nodes per wave.
// ---------------------------------------------------------------------------
__global__ __launch_bounds__(256) void node_gates_kernel(
    const float* __restrict__ h, const float* __restrict__ dvec,
    const float* __restrict__ Wl, const float* __restrict__ Wh,
    ushort_t* __restrict__ hbf,
    float4* __restrict__ gdst4, float4* __restrict__ gsrc4)
{
    int tid = threadIdx.x;
    int lane = tid & 63;
    int half = lane >> 5;
    int l32 = lane & 31;
    int node = blockIdx.x * 8 + (tid >> 6) * 2 + half;   // N_NODES % 8 == 0

    float2 hv2 = *(const float2*)(h + (size_t)node * 64 + l32 * 2);
    uint pk = (uint)f2bf(hv2.x) | ((uint)f2bf(hv2.y) << 16);
    ((uint*)hbf)[(size_t)node * 32 + l32] = pk;

    float pld = hv2.x * Wl[2 * l32]      + hv2.y * Wl[2 * l32 + 1];
    float pls = hv2.x * Wl[64 + 2 * l32] + hv2.y * Wl[64 + 2 * l32 + 1];
    float phd = hv2.x * Wh[2 * l32]      + hv2.y * Wh[2 * l32 + 1];
    float phs = hv2.x * Wh[64 + 2 * l32] + hv2.y * Wh[64 + 2 * l32 + 1];
    #pragma unroll
    for (int m = 16; m >= 1; m >>= 1) {     // stays within each 32-lane half
        pld += __shfl_xor(pld, m);
        pls += __shfl_xor(pls, m);
        phd += __shfl_xor(phd, m);
        phs += __shfl_xor(phs, m);
    }
    if (l32 == 0) {
        float d = dvec[node];
        gdst4[node] = make_float4(pld, phd, d, 0.f);
        gsrc4[node] = make_float4(pls, phs, d, 0.f);
    }
}

// ---------------------------------------------------------------------------
// K2: per-tile bucket histogram (int LDS atomics) -> T[tile][bucket]
// ---------------------------------------------------------------------------
__global__ __launch_bounds__(512) void bucket_hist_kernel(const int* __restrict__ dst,
                                                          int* __restrict__ T) {
    __shared__ int hist[NB];
    int tid = threadIdx.x;
    for (int i = tid; i < NB; i += 512) hist[i] = 0;
    __syncthreads();
    int base = blockIdx.x * TILE;
    #pragma unroll
    for (int j = 0; j < TILE / 512; ++j) {
        int e = base + j * 512 + tid;
        if (e < N_EDGES) atomicAdd(&hist[dst[e] >> 5], 1);
    }
    __syncthreads();
    int* row = T + (size_t)blockIdx.x * NB;
    for (int i = tid; i < NB; i += 512) row[i] = hist[i];
}

// ---------------------------------------------------------------------------
// K3a pass 1: within-group column scan of T (GT tiles per group).
// ---------------------------------------------------------------------------
__global__ __launch_bounds__(1024) void scanA1_kernel(int* __restrict__ T,
                                                      int* __restrict__ S) {
    int b = blockIdx.x * 1024 + threadIdx.x;
    if (b >= NB) return;
    int g = blockIdx.y;
    int run = 0;
    #pragma unroll
    for (int w = g * GT; w < g * GT + GT; ++w) {
        int idx = w * NB + b;
        int v = T[idx];
        T[idx] = run;
        run += v;
    }
    S[(size_t)g * NB + b] = run;
}

// ---------------------------------------------------------------------------
// K3a pass 2: exclusive scan of S over the GRP groups, per bucket.
// ---------------------------------------------------------------------------
__global__ __launch_bounds__(1024) void scanA2_kernel(int* __restrict__ S,
                                                      int* __restrict__ totG) {
    int b = blockIdx.x * 1024 + threadIdx.x;
    if (b >= NB) return;
    int run = 0;
    #pragma unroll
    for (int g = 0; g < GRP; ++g) {
        int idx = g * NB + b;
        int v = S[idx];
        S[idx] = run;
        run += v;
    }
    totG[b] = run;
}

// ---------------------------------------------------------------------------
// K3b: exclusive scan of totG[NB] -> baseG, bucketoffs. One block.
// Also performs the Wr transpose (fused).
// ---------------------------------------------------------------------------
__global__ __launch_bounds__(1024) void scanB_kernel(const int* __restrict__ totG,
                                                     int* __restrict__ baseG,
                                                     int* __restrict__ bucketoffs,
                                                     const float* __restrict__ Wr,
                                                     float* __restrict__ wrt) {
    int tid = threadIdx.x;
    // fused transpose: wrt[k][c] = Wr[c][k]
    for (int idx = tid; idx < 64 * 128; idx += 1024) {
        int c = idx >> 7;
        int k = idx & 127;
        wrt[k * 64 + c] = Wr[idx];
    }

    __shared__ int scan_lds[1024];
    int a[4];
    int s = 0;
    #pragma unroll
    for (int i = 0; i < 4; ++i) {
        int b = tid * 4 + i;
        a[i] = (b < NB) ? totG[b] : 0;
        s += a[i];
    }
    scan_lds[tid] = s;
    __syncthreads();
    for (int d = 1; d < 1024; d <<= 1) {
        int v = (tid >= d) ? scan_lds[tid - d] : 0;
        __syncthreads();
        scan_lds[tid] += v;
        __syncthreads();
    }
    int excl = scan_lds[tid] - s;
    int total = scan_lds[1023];
    #pragma unroll
    for (int i = 0; i < 4; ++i) {
        int b = tid * 4 + i;
        if (b < NB) { baseG[b] = excl; bucketoffs[b] = excl; }
        excl += a[i];
    }
    if (tid == 0) bucketoffs[NB] = total;
}

// ---------------------------------------------------------------------------
// K4: place edges into bucket-partitioned ebuf. LDS int cursors only.
// ---------------------------------------------------------------------------
__global__ __launch_bounds__(512) void place_kernel(
    const int* __restrict__ src, const int* __restrict__ dst,
    const int* __restrict__ T, const int* __restrict__ S,
    const int* __restrict__ baseG,
    const float4* __restrict__ gdst4, const float4* __restrict__ gsrc4,
    const float* __restrict__ bl, const float* __restrict__ bh,
    uint2* __restrict__ ebuf)
{
    __shared__ int cur[NB];
    int tid = threadIdx.x;
    const int* row  = T + (size_t)blockIdx.x * NB;
    const int* Srow = S + (size_t)(blockIdx.x / GT) * NB;
    for (int i = tid; i < NB; i += 512) cur[i] = row[i] + Srow[i] + baseG[i];
    __syncthreads();

    float bl0 = bl[0], bh0 = bh[0];
    int base = blockIdx.x * TILE;
    #pragma unroll
    for (int j = 0; j < TILE / 512; ++j) {
        int e = base + j * 512 + tid;
        if (e >= N_EDGES) continue;
        int t = dst[e];
        int s = src[e];
        float4 gt = gdst4[t];
        float4 gs = gsrc4[s];
        float xl = gt.x + gs.x + bl0;
        float xh = gt.y + gs.y + bh0;
        float ll = xl > 0.f ? xl : -P_L * xl;   // leaky, always >= 0
        float hh = xh > 0.f ? xh : -P_H * xh;
        float dd = gt.z * gs.z;
        float el =  tanh_pos(ll) * dd;
        float eh = -tanh_pos(hh) * dd;
        uint ge = (uint)__half_as_ushort(__float2half_rn(el))
                | ((uint)__half_as_ushort(__float2half_rn(eh)) << 16);
        int b  = t >> 5;
        uint dl = (uint)(t & 31);
        int pos = atomicAdd(&cur[b], 1);        // int LDS atomic
        ebuf[pos] = make_uint2((uint)s | (dl << 17), ge);
    }
}

// ---------------------------------------------------------------------------
// K5: per-bucket accumulate + fused Wr transform. 512 threads/block.
// Round-3 structure plus: (a) prefetch of both 64B lines of each record's
// h-row, issued before the first barrier -> phase-4 gathers hit warm L1/L2
// (serial chain latency converted to one parallel exposure absorbed by the
// sort phases); (b) wave-aggregated LDS atomics (5-ballot match, leader-only
// add) in phases 1+3 -> ~2x less atomic serialization; (c) v_pk_fma_f32
// packed math in phase 4 and phase 5.
// ---------------------------------------------------------------------------
__global__ __launch_bounds__(512) void accum_final_kernel(
    const int* __restrict__ bucketoffs, const uint2* __restrict__ ebuf,
    const ushort_t* __restrict__ hbf, const float* __restrict__ wrt,
    const float* __restrict__ br, float* __restrict__ out)
{
    __shared__ float z[NPB * ZS];        // 16.9 KB
    __shared__ uint2 srec[CAP];          // 6 KB
    __shared__ int ncount[NPB];
    __shared__ int nbase[NPB];
    __shared__ int ncur[NPB];

    int tid = threadIdx.x;
    int lane = tid & 63;
    int bk = blockIdx.x;
    int beg = bucketoffs[bk];
    int end = bucketoffs[bk + 1];
    int cnt = end - beg;
    if (cnt > CAP) cnt = CAP;    // statistically impossible (mean 512, +11 sigma)

    if (tid < NPB) ncount[tid] = 0;

    // single coalesced global pass: records live in VGPRs
    bool hA = tid < cnt;
    bool hB = tid + 512 < cnt;
    uint2 rA = hA ? ebuf[beg + tid] : make_uint2(0, 0);
    uint2 rB = hB ? ebuf[beg + tid + 512] : make_uint2(0, 0);

    // prefetch: warm BOTH 64B lines of each record's 128B h-row. The first
    // __syncthreads drains vmcnt anyway; all 2048 touches fly in parallel
    // while phases 1-3 run, so phase-4's serial chains hit warm cache.
    {
        const uint* pa = (const uint*)(hbf + (size_t)(rA.x & 0x1FFFF) * 64);
        const uint* pb = (const uint*)(hbf + (size_t)(rB.x & 0x1FFFF) * 64);
        uint p0 = hA ? pa[0]  : 0u;
        uint p1 = hA ? pa[16] : 0u;    // +64 B
        uint p2 = hB ? pb[0]  : 0u;
        uint p3 = hB ? pb[16] : 0u;
        asm volatile("" :: "v"(p0), "v"(p1), "v"(p2), "v"(p3));
    }
    __syncthreads();

    int dlA = (int)((rA.x >> 17) & 31u);
    int dlB = (int)((rB.x >> 17) & 31u);

    // phase 1: wave-aggregated histogram (leader lane adds popcount)
    unsigned long long mA = match_dl(dlA, hA);
    if (hA && lane == (int)__builtin_ctzll(mA))
        atomicAdd(&ncount[dlA], (int)__popcll(mA));
    unsigned long long mB = match_dl(dlB, hB);
    if (hB && lane == (int)__builtin_ctzll(mB))
        atomicAdd(&ncount[dlB], (int)__popcll(mB));
    __syncthreads();

    // phase 2: exclusive scan of 32 counts (lanes 0..31 of wave 0)
    if (tid < 32) {
        int v = ncount[tid];
        int p = v;
        #pragma unroll
        for (int d = 1; d < 32; d <<= 1) {
            int x = __shfl_up(p, d);
            if (tid >= d) p += x;
        }
        nbase[tid] = p - v;
        ncur[tid]  = p - v;
    }
    __syncthreads();

    // phase 3: counting-sort scatter, wave-aggregated cursor bump
    if (hA) {
        int ldr = (int)__builtin_ctzll(mA);
        int base = 0;
        if (lane == ldr) base = atomicAdd(&ncur[dlA], (int)__popcll(mA));
        base = __shfl(base, ldr);
        int rank = (int)__popcll(mA & ((1ull << lane) - 1ull));
        srec[base + rank] = rA;
    }
    if (hB) {
        int ldr = (int)__builtin_ctzll(mB);
        int base = 0;
        if (lane == ldr) base = atomicAdd(&ncur[dlB], (int)__popcll(mB));
        base = __shfl(base, ldr);
        int rank = (int)__popcll(mB & ((1ull << lane) - 1ull));
        srec[base + rank] = rB;
    }
    __syncthreads();

    // phase 4: subgroup sg (8 lanes) = node sg>>1, parity sg&1
    int sg = tid >> 3;            // 0..63
    int l8 = tid & 7;
    int node4 = sg >> 1;
    int par = sg & 1;
    int rbeg = nbase[node4];
    int rend = ncur[node4];       // nbase + count

    f2 acc[8];
    #pragma unroll
    for (int j = 0; j < 8; ++j) acc[j] = (f2){0.f, 0.f};

    int k = rbeg + par;
    // batch-4 over this parity's records (typical chain ~4 -> one exposure)
    for (; k + 6 < rend; k += 8) {
        uint2 r0 = srec[k];       // subgroup-uniform addr: LDS broadcast
        uint2 r1 = srec[k + 2];
        uint2 r2 = srec[k + 4];
        uint2 r3 = srec[k + 6];
        uint4 h0 = *(const uint4*)(hbf + (size_t)(r0.x & 0x1FFFF) * 64 + l8 * 8);
        uint4 h1 = *(const uint4*)(hbf + (size_t)(r1.x & 0x1FFFF) * 64 + l8 * 8);
        uint4 h2 = *(const uint4*)(hbf + (size_t)(r2.x & 0x1FFFF) * 64 + l8 * 8);
        uint4 h3 = *(const uint4*)(hbf + (size_t)(r3.x & 0x1FFFF) * 64 + l8 * 8);
        fma16(r0.y, h0, acc);
        fma16(r1.y, h1, acc);
        fma16(r2.y, h2, acc);
        fma16(r3.y, h3, acc);
    }
    for (; k < rend; k += 2) {
        uint2 r0 = srec[k];
        uint4 hv = *(const uint4*)(hbf + (size_t)(r0.x & 0x1FFFF) * 64 + l8 * 8);
        fma16(r0.y, hv, acc);
    }

    float* zp = &z[node4 * ZS + l8 * 8];
    if (par == 0) {
        *(float4*)(zp + 0)  = make_float4(acc[0].x, acc[0].y, acc[1].x, acc[1].y);
        *(float4*)(zp + 4)  = make_float4(acc[2].x, acc[2].y, acc[3].x, acc[3].y);
        *(float4*)(zp + 64) = make_float4(acc[4].x, acc[4].y, acc[5].x, acc[5].y);
        *(float4*)(zp + 68) = make_float4(acc[6].x, acc[6].y, acc[7].x, acc[7].y);
    }
    __syncthreads();
    if (par == 1) {
        float4 z0 = *(float4*)(zp + 0);
        float4 z1 = *(float4*)(zp + 4);
        float4 z2 = *(float4*)(zp + 64);
        float4 z3 = *(float4*)(zp + 68);
        *(float4*)(zp + 0)  = make_float4(z0.x + acc[0].x, z0.y + acc[0].y, z0.z + acc[1].x, z0.w + acc[1].y);
        *(float4*)(zp + 4)  = make_float4(z1.x + acc[2].x, z1.y + acc[2].y, z1.z + acc[3].x, z1.w + acc[3].y);
        *(float4*)(zp + 64) = make_float4(z2.x + acc[4].x, z2.y + acc[4].y, z2.z + acc[5].x, z2.w + acc[5].y);
        *(float4*)(zp + 68) = make_float4(z3.x + acc[6].x, z3.y + acc[6].y, z3.z + acc[7].x, z3.w + acc[7].y);
    }
    __syncthreads();

    // phase 5: fused final transform out[n] = z[n] . wrt + br (pk-fma)
    int node = tid >> 4;          // 0..31
    int g = tid & 15;             // 4-col group
    f2 fa0 = {0.f, 0.f}, fa1 = {0.f, 0.f};
    const float* zrow = z + node * ZS;   // 16B-aligned
    #pragma unroll 2
    for (int kk = 0; kk < 128; kk += 4) {
        float4 z4 = *(const float4*)(zrow + kk);
        const float* wp = wrt + kk * 64 + g * 4;
        float4 w0 = *(const float4*)(wp);
        float4 w1 = *(const float4*)(wp + 64);
        float4 w2 = *(const float4*)(wp + 128);
        float4 w3 = *(const float4*)(wp + 192);
        fa0 += (f2){w0.x, w0.y} * z4.x; fa1 += (f2){w0.z, w0.w} * z4.x;
        fa0 += (f2){w1.x, w1.y} * z4.y; fa1 += (f2){w1.z, w1.w} * z4.y;
        fa0 += (f2){w2.x, w2.y} * z4.z; fa1 += (f2){w2.z, w2.w} * z4.z;
        fa0 += (f2){w3.x, w3.y} * z4.w; fa1 += (f2){w3.z, w3.w} * z4.w;
    }
    int n = bk * NPB + node;
    float* op = out + (size_t)n * 64 + g * 4;
    const float* bp = br + g * 4;
    *(float4*)(op) = make_float4(fa0.x + bp[0], fa0.y + bp[1], fa1.x + bp[2], fa1.y + bp[3]);
}

// ---------------------------------------------------------------------------
extern "C" void kernel_launch(void* const* d_in, const int* in_sizes, int n_in,
                              void* d_out, int out_size, void* d_ws, size_t ws_size,
                              hipStream_t stream) {
    const float* h    = (const float*)d_in[0];
    const float* dvec = (const float*)d_in[1];
    const int*   src  = (const int*)  d_in[2];
    const int*   dst  = (const int*)  d_in[3];
    const float* Wl   = (const float*)d_in[4];
    const float* bl   = (const float*)d_in[5];
    const float* Wh   = (const float*)d_in[6];
    const float* bh   = (const float*)d_in[7];
    const float* Wr   = (const float*)d_in[8];
    const float* br   = (const float*)d_in[9];
    float* out = (float*)d_out;

    char* ws = (char*)d_ws;
    size_t off = 0;
    auto alloc = [&](size_t bytes) { char* p = ws + off; off += (bytes + 255) & ~size_t(255); return p; };

    ushort_t* hbf       = (ushort_t*)alloc((size_t)N_NODES * 64 * 2);     // 12.8 MB
    float4*   gdst4     = (float4*)  alloc((size_t)N_NODES * 16);         // 1.6 MB
    float4*   gsrc4     = (float4*)  alloc((size_t)N_NODES * 16);         // 1.6 MB
    float*    wrt       = (float*)   alloc(64 * 128 * 4);                 // 32 KB
    int*      T         = (int*)     alloc((size_t)NT * NB * 4);          // 9.8 MB
    int*      S         = (int*)     alloc((size_t)GRP * NB * 4);         // 350 KB
    int*      totG      = (int*)     alloc((size_t)NB * 4);
    int*      baseG     = (int*)     alloc((size_t)NB * 4);
    int*      bucketoffs= (int*)     alloc((size_t)(NB + 1) * 4);
    uint2*    ebuf      = (uint2*)   alloc((size_t)N_EDGES * 8);          // 12.8 MB

    node_gates_kernel<<<N_NODES / 8, 256, 0, stream>>>(h, dvec, Wl, Wh, hbf, gdst4, gsrc4);
    bucket_hist_kernel<<<NT, 512, 0, stream>>>(dst, T);
    {
        dim3 g1((NB + 1023) / 1024, GRP);
        scanA1_kernel<<<g1, 1024, 0, stream>>>(T, S);
    }
    scanA2_kernel<<<(NB + 1023) / 1024, 1024, 0, stream>>>(S, totG);
    scanB_kernel<<<1, 1024, 0, stream>>>(totG, baseG, bucketoffs, Wr, wrt);
    place_kernel<<<NT, 512, 0, stream>>>(src, dst, T, S, baseG, gdst4, gsrc4, bl, bh, ebuf);
    accum_final_kernel<<<NB, 512, 0, stream>>>(bucketoffs, ebuf, hbf, wrt, br, out);
}

// Round 5
// 285.368 us; speedup vs baseline: 1.0719x; 1.0719x over previous
//
#include <hip/hip_runtime.h>
#include <hip/hip_fp16.h>
#include <math.h>

#define N_NODES 100000
#define D_DIM   64
#define N_EDGES 1600000
#define P_L 0.5f
#define P_H 0.5f

#define NPB   32                       // nodes per bucket (exact: 32*3125=100000)
#define NB    3125                     // number of buckets
#define TILE  2048                     // edges per partition tile
#define NT    784                      // number of tiles
#define GRP   28                       // scan groups (GRP*GT == NT)
#define GT    28                       // tiles per scan group
#define CAPB  768                      // per-bucket record cap (mean 512, +11 sigma)
#define CAPH  512                      // per-half-bucket record cap (mean 256, +16 sigma)
#define ZS    132                      // z row stride (16B-aligned rows, bank-spread)

// NOTE (round-1): LDS float atomicAdd serializes (~3cy/lane) - never on hot path.
// NOTE (round-2): __launch_bounds__ pin below register pressure -> scratch spill
//   (WRITE_SIZE 25->597 MB). No pins.
// NOTE (round-4): prefetching the gather set across a barrier BACKFIRED:
//   hbf (12.8MB) is L3-resident but NOT L2-resident (4MB/XCD), so prefetched
//   lines evicted before use -> FETCH_SIZE 82->125MB, +8us. Prefetch only
//   when the working set is L2-resident. Wave-aggregated LDS atomics and
//   v_pk_fma_f32 are keepers (conflicts -18%, VGPR -4).
// This round: half-bucket blocks (256 thr) -> 8 independent barrier groups
//   per CU instead of 4; K-side unchanged.

typedef unsigned int uint;
typedef unsigned short ushort_t;
typedef float f2 __attribute__((ext_vector_type(2)));   // -> v_pk_fma_f32

__device__ inline ushort_t f2bf(float f) {
    uint u = __float_as_uint(f);
    uint r = (u + 0x7fffu + ((u >> 16) & 1u)) >> 16;
    return (ushort_t)r;
}

// fast tanh for x >= 0
__device__ inline float tanh_pos(float x) {
    return 1.f - 2.f / (__expf(2.f * x) + 1.f);
}

// 16 FMAs of one record into the per-lane accumulator (8 x v_pk_fma_f32)
__device__ inline void fma16(uint gy, uint4 hv, f2* acc) {
    float el = __half2float(__ushort_as_half((unsigned short)(gy & 0xffffu)));
    float eh = __half2float(__ushort_as_half((unsigned short)(gy >> 16)));
    f2 f01 = {__uint_as_float(hv.x << 16), __uint_as_float(hv.x & 0xffff0000u)};
    f2 f23 = {__uint_as_float(hv.y << 16), __uint_as_float(hv.y & 0xffff0000u)};
    f2 f45 = {__uint_as_float(hv.z << 16), __uint_as_float(hv.z & 0xffff0000u)};
    f2 f67 = {__uint_as_float(hv.w << 16), __uint_as_float(hv.w & 0xffff0000u)};
    acc[0] += f01 * el; acc[1] += f23 * el; acc[2] += f45 * el; acc[3] += f67 * el;
    acc[4] += f01 * eh; acc[5] += f23 * eh; acc[6] += f45 * eh; acc[7] += f67 * eh;
}

// lanes-with-same-dl mask via 4 ballots (dl in [0,16)); valid on active lanes
__device__ inline unsigned long long match4(int dl, bool active) {
    unsigned long long m = __ballot(active);
    #pragma unroll
    for (int b = 0; b < 4; ++b) {
        unsigned long long bal = __ballot(active && ((dl >> b) & 1));
        m &= ((dl >> b) & 1) ? bal : ~bal;
    }
    return m;
}

// ---------------------------------------------------------------------------
// K1: per-node gate projections + h -> bf16. TWO nodes per wave.
// ---------------------------------------------------------------------------
__global__ __launch_bounds__(256) void node_gates_kernel(
    const float* __restrict__ h, const float* __restrict__ dvec,
    const float* __restrict__ Wl, const float* __restrict__ Wh,
    ushort_t* __restrict__ hbf,
    float4* __restrict__ gdst4, float4* __restrict__ gsrc4)
{
    int tid = threadIdx.x;
    int lane = tid & 63;
    int half = lane >> 5;
    int l32 = lane & 31;
    int node = blockIdx.x * 8 + (tid >> 6) * 2 + half;   // N_NODES % 8 == 0

    float2 hv2 = *(const float2*)(h + (size_t)node * 64 + l32 * 2);
    uint pk = (uint)f2bf(hv2.x) | ((uint)f2bf(hv2.y) << 16);
    ((uint*)hbf)[(size_t)node * 32 + l32] = pk;

    float pld = hv2.x * Wl[2 * l32]      + hv2.y * Wl[2 * l32 + 1];
    float pls = hv2.x * Wl[64 + 2 * l32] + hv2.y * Wl[64 + 2 * l32 + 1];
    float phd = hv2.x * Wh[2 * l32]      + hv2.y * Wh[2 * l32 + 1];
    float phs = hv2.x * Wh[64 + 2 * l32] + hv2.y * Wh[64 + 2 * l32 + 1];
    #pragma unroll
    for (int m = 16; m >= 1; m >>= 1) {     // stays within each 32-lane half
        pld += __shfl_xor(pld, m);
        pls += __shfl_xor(pls, m);
        phd += __shfl_xor(phd, m);
        phs += __shfl_xor(phs, m);
    }
    if (l32 == 0) {
        float d = dvec[node];
        gdst4[node] = make_float4(pld, phd, d, 0.f);
        gsrc4[node] = make_float4(pls, phs, d, 0.f);
    }
}

// ---------------------------------------------------------------------------
// K2: per-tile bucket histogram (int LDS atomics) -> T[tile][bucket]
// ---------------------------------------------------------------------------
__global__ __launch_bounds__(512) void bucket_hist_kernel(const int* __restrict__ dst,
                                                          int* __restrict__ T) {
    __shared__ int hist[NB];
    int tid = threadIdx.x;
    for (int i = tid; i < NB; i += 512) hist[i] = 0;
    __syncthreads();
    int base = blockIdx.x * TILE;
    #pragma unroll
    for (int j = 0; j < TILE / 512; ++j) {
        int e = base + j * 512 + tid;
        if (e < N_EDGES) atomicAdd(&hist[dst[e] >> 5], 1);
    }
    __syncthreads();
    int* row = T + (size_t)blockIdx.x * NB;
    for (int i = tid; i < NB; i += 512) row[i] = hist[i];
}

// ---------------------------------------------------------------------------
// K3a pass 1: within-group column scan of T (GT tiles per group).
// ---------------------------------------------------------------------------
__global__ __launch_bounds__(1024) void scanA1_kernel(int* __restrict__ T,
                                                      int* __restrict__ S) {
    int b = blockIdx.x * 1024 + threadIdx.x;
    if (b >= NB) return;
    int g = blockIdx.y;
    int run = 0;
    #pragma unroll
    for (int w = g * GT; w < g * GT + GT; ++w) {
        int idx = w * NB + b;
        int v = T[idx];
        T[idx] = run;
        run += v;
    }
    S[(size_t)g * NB + b] = run;
}

// ---------------------------------------------------------------------------
// K3a pass 2: exclusive scan of S over the GRP groups, per bucket.
// ---------------------------------------------------------------------------
__global__ __launch_bounds__(1024) void scanA2_kernel(int* __restrict__ S,
                                                      int* __restrict__ totG) {
    int b = blockIdx.x * 1024 + threadIdx.x;
    if (b >= NB) return;
    int run = 0;
    #pragma unroll
    for (int g = 0; g < GRP; ++g) {
        int idx = g * NB + b;
        int v = S[idx];
        S[idx] = run;
        run += v;
    }
    totG[b] = run;
}

// ---------------------------------------------------------------------------
// K3b: exclusive scan of totG[NB] -> baseG, bucketoffs. One block.
// Also performs the Wr transpose (fused).
// ---------------------------------------------------------------------------
__global__ __launch_bounds__(1024) void scanB_kernel(const int* __restrict__ totG,
                                                     int* __restrict__ baseG,
                                                     int* __restrict__ bucketoffs,
                                                     const float* __restrict__ Wr,
                                                     float* __restrict__ wrt) {
    int tid = threadIdx.x;
    // fused transpose: wrt[k][c] = Wr[c][k]
    for (int idx = tid; idx < 64 * 128; idx += 1024) {
        int c = idx >> 7;
        int k = idx & 127;
        wrt[k * 64 + c] = Wr[idx];
    }

    __shared__ int scan_lds[1024];
    int a[4];
    int s = 0;
    #pragma unroll
    for (int i = 0; i < 4; ++i) {
        int b = tid * 4 + i;
        a[i] = (b < NB) ? totG[b] : 0;
        s += a[i];
    }
    scan_lds[tid] = s;
    __syncthreads();
    for (int d = 1; d < 1024; d <<= 1) {
        int v = (tid >= d) ? scan_lds[tid - d] : 0;
        __syncthreads();
        scan_lds[tid] += v;
        __syncthreads();
    }
    int excl = scan_lds[tid] - s;
    int total = scan_lds[1023];
    #pragma unroll
    for (int i = 0; i < 4; ++i) {
        int b = tid * 4 + i;
        if (b < NB) { baseG[b] = excl; bucketoffs[b] = excl; }
        excl += a[i];
    }
    if (tid == 0) bucketoffs[NB] = total;
}

// ---------------------------------------------------------------------------
// K4: place edges into bucket-partitioned ebuf. LDS int cursors only.
// ---------------------------------------------------------------------------
__global__ __launch_bounds__(512) void place_kernel(
    const int* __restrict__ src, const int* __restrict__ dst,
    const int* __restrict__ T, const int* __restrict__ S,
    const int* __restrict__ baseG,
    const float4* __restrict__ gdst4, const float4* __restrict__ gsrc4,
    const float* __restrict__ bl, const float* __restrict__ bh,
    uint2* __restrict__ ebuf)
{
    __shared__ int cur[NB];
    int tid = threadIdx.x;
    const int* row  = T + (size_t)blockIdx.x * NB;
    const int* Srow = S + (size_t)(blockIdx.x / GT) * NB;
    for (int i = tid; i < NB; i += 512) cur[i] = row[i] + Srow[i] + baseG[i];
    __syncthreads();

    float bl0 = bl[0], bh0 = bh[0];
    int base = blockIdx.x * TILE;
    #pragma unroll
    for (int j = 0; j < TILE / 512; ++j) {
        int e = base + j * 512 + tid;
        if (e >= N_EDGES) continue;
        int t = dst[e];
        int s = src[e];
        float4 gt = gdst4[t];
        float4 gs = gsrc4[s];
        float xl = gt.x + gs.x + bl0;
        float xh = gt.y + gs.y + bh0;
        float ll = xl > 0.f ? xl : -P_L * xl;   // leaky, always >= 0
        float hh = xh > 0.f ? xh : -P_H * xh;
        float dd = gt.z * gs.z;
        float el =  tanh_pos(ll) * dd;
        float eh = -tanh_pos(hh) * dd;
        uint ge = (uint)__half_as_ushort(__float2half_rn(el))
                | ((uint)__half_as_ushort(__float2half_rn(eh)) << 16);
        int b  = t >> 5;
        uint dl = (uint)(t & 31);
        int pos = atomicAdd(&cur[b], 1);        // int LDS atomic
        ebuf[pos] = make_uint2((uint)s | (dl << 17), ge);
    }
}

// ---------------------------------------------------------------------------
// K5: per-HALF-bucket accumulate + fused Wr transform. 256 threads/block,
// grid = 2*NB. Block (bk, hf) owns nodes bk*32 + hf*16 .. +15. It scans the
// whole bucket's records (<=3/thread), filters by dl>>4==hf, counting-sorts
// the ~256 matches into LDS, then runs the proven batch-4 register
// accumulation (chains ~8 per parity subgroup). 4-wave blocks -> 8
// independent barrier groups per CU (was 4): barrier drains and memory
// exposures from different groups overlap. Wave-aggregated LDS atomics +
// v_pk_fma_f32 kept from round 4; prefetch dropped (round-4 lesson).
// ---------------------------------------------------------------------------
__global__ __launch_bounds__(256) void accum_final_kernel(
    const int* __restrict__ bucketoffs, const uint2* __restrict__ ebuf,
    const ushort_t* __restrict__ hbf, const float* __restrict__ wrt,
    const float* __restrict__ br, float* __restrict__ out)
{
    __shared__ float z[16 * ZS];         // 8.4 KB
    __shared__ uint2 srec[CAPH];         // 4 KB
    __shared__ int ncount[16];
    __shared__ int nbase[16];
    __shared__ int ncur[16];

    int tid = threadIdx.x;
    int lane = tid & 63;
    int bk = blockIdx.x >> 1;
    int hf = blockIdx.x & 1;
    int beg = bucketoffs[bk];
    int end = bucketoffs[bk + 1];
    int cnt = end - beg;
    if (cnt > CAPB) cnt = CAPB;   // statistically impossible (mean 512, +11 sigma)

    if (tid < 16) ncount[tid] = 0;

    // coalesced pass over the bucket's records (records live in VGPRs)
    bool hA = tid < cnt;
    bool hB = tid + 256 < cnt;
    bool hC = tid + 512 < cnt;
    uint2 rA = hA ? ebuf[beg + tid]       : make_uint2(0, 0);
    uint2 rB = hB ? ebuf[beg + tid + 256] : make_uint2(0, 0);
    uint2 rC = hC ? ebuf[beg + tid + 512] : make_uint2(0, 0);
    __syncthreads();

    int dA5 = (int)((rA.x >> 17) & 31u);
    int dB5 = (int)((rB.x >> 17) & 31u);
    int dC5 = (int)((rC.x >> 17) & 31u);
    bool oA = hA && ((dA5 >> 4) == hf);   // ownership filter
    bool oB = hB && ((dB5 >> 4) == hf);
    bool oC = hC && ((dC5 >> 4) == hf);
    int dlA = dA5 & 15, dlB = dB5 & 15, dlC = dC5 & 15;

    // phase 1: wave-aggregated histogram (leader lane adds popcount)
    unsigned long long mA = match4(dlA, oA);
    if (oA && lane == (int)__builtin_ctzll(mA))
        atomicAdd(&ncount[dlA], (int)__popcll(mA));
    unsigned long long mB = match4(dlB, oB);
    if (oB && lane == (int)__builtin_ctzll(mB))
        atomicAdd(&ncount[dlB], (int)__popcll(mB));
    unsigned long long mC = match4(dlC, oC);
    if (oC && lane == (int)__builtin_ctzll(mC))
        atomicAdd(&ncount[dlC], (int)__popcll(mC));
    __syncthreads();

    // phase 2: exclusive scan of 16 counts (lanes 0..15 of wave 0)
    if (tid < 16) {
        int v = ncount[tid];
        int p = v;
        #pragma unroll
        for (int d = 1; d < 16; d <<= 1) {
            int x = __shfl_up(p, d);
            if (tid >= d) p += x;
        }
        nbase[tid] = p - v;
        ncur[tid]  = p - v;
    }
    __syncthreads();

    // phase 3: counting-sort scatter, wave-aggregated cursor bump
    if (oA) {
        int ldr = (int)__builtin_ctzll(mA);
        int base = 0;
        if (lane == ldr) base = atomicAdd(&ncur[dlA], (int)__popcll(mA));
        base = __shfl(base, ldr);
        int pos = base + (int)__popcll(mA & ((1ull << lane) - 1ull));
        if (pos < CAPH) srec[pos] = rA;
    }
    if (oB) {
        int ldr = (int)__builtin_ctzll(mB);
        int base = 0;
        if (lane == ldr) base = atomicAdd(&ncur[dlB], (int)__popcll(mB));
        base = __shfl(base, ldr);
        int pos = base + (int)__popcll(mB & ((1ull << lane) - 1ull));
        if (pos < CAPH) srec[pos] = rB;
    }
    if (oC) {
        int ldr = (int)__builtin_ctzll(mC);
        int base = 0;
        if (lane == ldr) base = atomicAdd(&ncur[dlC], (int)__popcll(mC));
        base = __shfl(base, ldr);
        int pos = base + (int)__popcll(mC & ((1ull << lane) - 1ull));
        if (pos < CAPH) srec[pos] = rC;
    }
    __syncthreads();

    // phase 4: subgroup sg (8 lanes) = node sg>>1, parity sg&1
    int sg = tid >> 3;            // 0..31
    int l8 = tid & 7;
    int node4 = sg >> 1;          // 0..15
    int par = sg & 1;
    int rbeg = nbase[node4];
    int rend = ncur[node4];       // nbase + count
    if (rend > CAPH) rend = CAPH;

    f2 acc[8];
    #pragma unroll
    for (int j = 0; j < 8; ++j) acc[j] = (f2){0.f, 0.f};

    int k = rbeg + par;
    // batch-4 over this parity's records
    for (; k + 6 < rend; k += 8) {
        uint2 r0 = srec[k];       // subgroup-uniform addr: LDS broadcast
        uint2 r1 = srec[k + 2];
        uint2 r2 = srec[k + 4];
        uint2 r3 = srec[k + 6];
        uint4 h0 = *(const uint4*)(hbf + (size_t)(r0.x & 0x1FFFF) * 64 + l8 * 8);
        uint4 h1 = *(const uint4*)(hbf + (size_t)(r1.x & 0x1FFFF) * 64 + l8 * 8);
        uint4 h2 = *(const uint4*)(hbf + (size_t)(r2.x & 0x1FFFF) * 64 + l8 * 8);
        uint4 h3 = *(const uint4*)(hbf + (size_t)(r3.x & 0x1FFFF) * 64 + l8 * 8);
        fma16(r0.y, h0, acc);
        fma16(r1.y, h1, acc);
        fma16(r2.y, h2, acc);
        fma16(r3.y, h3, acc);
    }
    for (; k < rend; k += 2) {
        uint2 r0 = srec[k];
        uint4 hv = *(const uint4*)(hbf + (size_t)(r0.x & 0x1FFFF) * 64 + l8 * 8);
        fma16(r0.y, hv, acc);
    }

    float* zp = &z[node4 * ZS + l8 * 8];
    if (par == 0) {
        *(float4*)(zp + 0)  = make_float4(acc[0].x, acc[0].y, acc[1].x, acc[1].y);
        *(float4*)(zp + 4)  = make_float4(acc[2].x, acc[2].y, acc[3].x, acc[3].y);
        *(float4*)(zp + 64) = make_float4(acc[4].x, acc[4].y, acc[5].x, acc[5].y);
        *(float4*)(zp + 68) = make_float4(acc[6].x, acc[6].y, acc[7].x, acc[7].y);
    }
    __syncthreads();
    if (par == 1) {
        float4 z0 = *(float4*)(zp + 0);
        float4 z1 = *(float4*)(zp + 4);
        float4 z2 = *(float4*)(zp + 64);
        float4 z3 = *(float4*)(zp + 68);
        *(float4*)(zp + 0)  = make_float4(z0.x + acc[0].x, z0.y + acc[0].y, z0.z + acc[1].x, z0.w + acc[1].y);
        *(float4*)(zp + 4)  = make_float4(z1.x + acc[2].x, z1.y + acc[2].y, z1.z + acc[3].x, z1.w + acc[3].y);
        *(float4*)(zp + 64) = make_float4(z2.x + acc[4].x, z2.y + acc[4].y, z2.z + acc[5].x, z2.w + acc[5].y);
        *(float4*)(zp + 68) = make_float4(z3.x + acc[6].x, z3.y + acc[6].y, z3.z + acc[7].x, z3.w + acc[7].y);
    }
    __syncthreads();

    // phase 5: fused final transform out[n] = z[n] . wrt + br (pk-fma)
    int node = tid >> 4;          // 0..15
    int g = tid & 15;             // 4-col group
    f2 fa0 = {0.f, 0.f}, fa1 = {0.f, 0.f};
    const float* zrow = z + node * ZS;   // 16B-aligned
    #pragma unroll 2
    for (int kk = 0; kk < 128; kk += 4) {
        float4 z4 = *(const float4*)(zrow + kk);
        const float* wp = wrt + kk * 64 + g * 4;
        float4 w0 = *(const float4*)(wp);
        float4 w1 = *(const float4*)(wp + 64);
        float4 w2 = *(const float4*)(wp + 128);
        float4 w3 = *(const float4*)(wp + 192);
        fa0 += (f2){w0.x, w0.y} * z4.x; fa1 += (f2){w0.z, w0.w} * z4.x;
        fa0 += (f2){w1.x, w1.y} * z4.y; fa1 += (f2){w1.z, w1.w} * z4.y;
        fa0 += (f2){w2.x, w2.y} * z4.z; fa1 += (f2){w2.z, w2.w} * z4.z;
        fa0 += (f2){w3.x, w3.y} * z4.w; fa1 += (f2){w3.z, w3.w} * z4.w;
    }
    int n = bk * NPB + hf * 16 + node;
    float* op = out + (size_t)n * 64 + g * 4;
    const float* bp = br + g * 4;
    *(float4*)(op) = make_float4(fa0.x + bp[0], fa0.y + bp[1], fa1.x + bp[2], fa1.y + bp[3]);
}

// ---------------------------------------------------------------------------
extern "C" void kernel_launch(void* const* d_in, const int* in_sizes, int n_in,
                              void* d_out, int out_size, void* d_ws, size_t ws_size,
                              hipStream_t stream) {
    const float* h    = (const float*)d_in[0];
    const float* dvec = (const float*)d_in[1];
    const int*   src  = (const int*)  d_in[2];
    const int*   dst  = (const int*)  d_in[3];
    const float* Wl   = (const float*)d_in[4];
    const float* bl   = (const float*)d_in[5];
    const float* Wh   = (const float*)d_in[6];
    const float* bh   = (const float*)d_in[7];
    const float* Wr   = (const float*)d_in[8];
    const float* br   = (const float*)d_in[9];
    float* out = (float*)d_out;

    char* ws = (char*)d_ws;
    size_t off = 0;
    auto alloc = [&](size_t bytes) { char* p = ws + off; off += (bytes + 255) & ~size_t(255); return p; };

    ushort_t* hbf       = (ushort_t*)alloc((size_t)N_NODES * 64 * 2);     // 12.8 MB
    float4*   gdst4     = (float4*)  alloc((size_t)N_NODES * 16);         // 1.6 MB
    float4*   gsrc4     = (float4*)  alloc((size_t)N_NODES * 16);         // 1.6 MB
    float*    wrt       = (float*)   alloc(64 * 128 * 4);                 // 32 KB
    int*      T         = (int*)     alloc((size_t)NT * NB * 4);          // 9.8 MB
    int*      S         = (int*)     alloc((size_t)GRP * NB * 4);         // 350 KB
    int*      totG      = (int*)     alloc((size_t)NB * 4);
    int*      baseG     = (int*)     alloc((size_t)NB * 4);
    int*      bucketoffs= (int*)     alloc((size_t)(NB + 1) * 4);
    uint2*    ebuf      = (uint2*)   alloc((size_t)N_EDGES * 8);          // 12.8 MB

    node_gates_kernel<<<N_NODES / 8, 256, 0, stream>>>(h, dvec, Wl, Wh, hbf, gdst4, gsrc4);
    bucket_hist_kernel<<<NT, 512, 0, stream>>>(dst, T);
    {
        dim3 g1((NB + 1023) / 1024, GRP);
        scanA1_kernel<<<g1, 1024, 0, stream>>>(T, S);
    }
    scanA2_kernel<<<(NB + 1023) / 1024, 1024, 0, stream>>>(S, totG);
    scanB_kernel<<<1, 1024, 0, stream>>>(totG, baseG, bucketoffs, Wr, wrt);
    place_kernel<<<NT, 512, 0, stream>>>(src, dst, T, S, baseG, gdst4, gsrc4, bl, bh, ebuf);
    accum_final_kernel<<<NB * 2, 256, 0, stream>>>(bucketoffs, ebuf, hbf, wrt, br, out);
}